// Round 8
// baseline (173.632 us; speedup 1.0000x reference)
//
#include <hip/hip_runtime.h>

// DiceLoss: B=2, C=14, D=48, H=256, W=256, organs 1..13, weights all 1.0.
// Per batch b: S = sum of pred at target channel (t in 1..13),
//              Q = sum over c=1..13 of pred[c]^2, cnt = #{t>=1}.
// dice_stage = 2S/(Q + cnt + 13*EPS); out = mean_b(2 - dice1 - dice2).
//
// R8 = R6 (LDS ring, global_load_lds w16 aux=0, counted vmcnt(2), no
// barriers, 8 blocks/CU = 32 waves/CU) with ONE change: stage-specialized
// blocks. 2048 blocks = 2 stages x 2 batches x 512 windows; each block
// streams one stage's 13 channels over a 1536-group window -> 24 KB
// contiguous runs (2x R6), half the pred streams. Target read per stage
// (2x logical, 25 MB unique - L3 absorbs). cnt counted by stage-0 only.
// NT policy reverted (R7: -6%).

namespace {
constexpr int BATCH = 2;
constexpr int CH = 14;
constexpr int ORGANS = 13;
constexpr unsigned NV4 = 786432u;        // vec4 groups per (b, channel) slice
constexpr int TPB = 256;
constexpr int NBLK = 2048;               // 2 stages x 2 batches x 512 windows
constexpr unsigned WIN = 1536u;          // groups per window (512*1536 = NV4)
constexpr int KT = 6;                    // tiles per channel: WIN/256
constexpr int NBUF = 4;                  // ring slots (4 KB each) -> 16 KB
constexpr double EPS = 1e-05;
}

// global -> LDS async, 16B/lane, default cache policy.
#define LOADLDS(srcptr, slot)                                              \
    __builtin_amdgcn_global_load_lds(                                      \
        (const __attribute__((address_space(1))) unsigned*)(srcptr),       \
        (__attribute__((address_space(3))) unsigned*)&ring[(slot)][ldsq],  \
        16, 0, 0)

__global__ __launch_bounds__(TPB, 8) void dice_lds(
    const float* __restrict__ p1g, const float* __restrict__ p2g,
    const int* __restrict__ tg, double* __restrict__ part)
{
    __shared__ float4 ring[NBUF][TPB];   // 16 KB ring
    __shared__ float red[4][3];

    const unsigned blk = blockIdx.x;
    const unsigned sb = blk >> 10;               // stage 0/1
    const unsigned b = (blk >> 9) & 1u;          // batch
    const unsigned w0 = (blk & 511u) * WIN;      // window start (groups)
    const unsigned tid = threadIdx.x;
    const unsigned wid = tid >> 6;
    const unsigned ldsq = wid * 64u;             // this wave's ring quarter

    // Channel walker: this stage's channel 1, this window (float4 idx space).
    const float* pg = sb ? p2g : p1g;
    const float4* aS = reinterpret_cast<const float4*>(pg)
        + (unsigned long long)(b * CH + 1) * NV4 + w0 + tid;

    // Prologue: 3 tiles of channel 1 in flight before the target read.
    LOADLDS(aS + 0 * TPB, 0);
    LOADLDS(aS + 1 * TPB, 1);
    LOADLDS(aS + 2 * TPB, 2);

    // Target window: KT int4 per thread; pack labels into bytes.
    unsigned tw[KT];
    float cn = 0.f;
    {
        const int4* __restrict__ pT =
            reinterpret_cast<const int4*>(tg) + b * NV4 + w0;
        #pragma unroll
        for (int k = 0; k < KT; ++k) {
            const int4 t = pT[k * TPB + tid];
            cn += (float)((t.x > 0) + (t.y > 0) + (t.z > 0) + (t.w > 0));
            tw[k] = (unsigned)t.x | ((unsigned)t.y << 8)
                  | ((unsigned)t.z << 16) | ((unsigned)t.w << 24);
        }
    }

    float s = 0.f, q = 0.f;
    unsigned cc = 1;                             // current organ id

    auto acc4 = [&](const float4 A, int k) {
        const unsigned t4 = tw[k];
        q = fmaf(A.x, A.x, q); q = fmaf(A.y, A.y, q);
        q = fmaf(A.z, A.z, q); q = fmaf(A.w, A.w, q);
        const bool ex = ((t4 & 255u) == cc);
        const bool ey = (((t4 >> 8) & 255u) == cc);
        const bool ez = (((t4 >> 16) & 255u) == cc);
        const bool ew = ((t4 >> 24) == cc);
        s += (ex ? A.x : 0.f) + (ey ? A.y : 0.f)
           + (ez ? A.z : 0.f) + (ew ? A.w : 0.f);
    };

    // One channel: consume its 6 tiles, issue the next channel's 6.
    // Tile ti = 6c + p; slot = ti & 3; SB = (6c) & 3 alternates 0/2.
    auto chan = [&](const int SB) {
        #pragma unroll
        for (int p = 0; p < 6; ++p) {
            asm volatile("s_waitcnt vmcnt(2)" ::: "memory");
            if (p < 3) LOADLDS(aS + (p + 3) * TPB, (SB + p + 3) & 3);
            else       LOADLDS(aS + NV4 + (p - 3) * TPB, (SB + p + 3) & 3);
            acc4(ring[(SB + p) & 3][tid], p);
        }
        aS += NV4; ++cc;
    };

    #pragma unroll 1
    for (int cp = 0; cp < 6; ++cp) { chan(0); chan(2); }   // channels 1..12

    // Peel channel 13 (SB = 72 & 3 = 0): issue its tail, then drain.
    #pragma unroll
    for (int p = 0; p < 3; ++p) {
        asm volatile("s_waitcnt vmcnt(2)" ::: "memory");
        LOADLDS(aS + (p + 3) * TPB, (p + 3) & 3);
        acc4(ring[p & 3][tid], p);
    }
    asm volatile("s_waitcnt vmcnt(2)" ::: "memory");
    acc4(ring[3][tid], 3);
    asm volatile("s_waitcnt vmcnt(1)" ::: "memory");
    acc4(ring[0][tid], 4);
    asm volatile("s_waitcnt vmcnt(0)" ::: "memory");
    acc4(ring[1][tid], 5);

    // ---- Block reduction: wave shuffle then LDS across 4 waves ----
    float vals[3] = {s, q, cn};
    #pragma unroll
    for (int k = 0; k < 3; ++k) {
        float v = vals[k];
        #pragma unroll
        for (int off = 32; off > 0; off >>= 1) v += __shfl_down(v, off, 64);
        vals[k] = v;
    }
    const int lane = tid & 63;
    if (lane == 0) {
        #pragma unroll
        for (int k = 0; k < 3; ++k) red[wid][k] = vals[k];
    }
    __syncthreads();
    if (tid == 0) {
        #pragma unroll
        for (int k = 0; k < 3; ++k)
            part[blk * 3 + k] =
                (double)(red[0][k] + red[1][k] + red[2][k] + red[3][k]);
    }
}

__global__ __launch_bounds__(256) void dice_final(
    const double* __restrict__ part, float* __restrict__ out)
{
    // 4 waves <-> 4 (stage, batch) combos; each reduces its 512 windows.
    __shared__ double redd[4][3];
    const int tid = threadIdx.x, lane = tid & 63, wv = tid >> 6;
    const unsigned sb = (unsigned)wv >> 1, b = (unsigned)wv & 1u;
    double loc[3] = {0, 0, 0};
    for (unsigned i = (unsigned)lane; i < 512u; i += 64u) {
        const double* p = part + ((sb << 10) | (b << 9) | i) * 3u;
        loc[0] += p[0]; loc[1] += p[1]; loc[2] += p[2];
    }
    #pragma unroll
    for (int k = 0; k < 3; ++k) {
        double v = loc[k];
        #pragma unroll
        for (int off = 32; off > 0; off >>= 1) v += __shfl_down(v, off, 64);
        loc[k] = v;
    }
    if (lane == 0) {
        #pragma unroll
        for (int k = 0; k < 3; ++k) redd[wv][k] = loc[k];
    }
    __syncthreads();
    if (tid == 0) {
        double total = 0.0;
        #pragma unroll
        for (int bb = 0; bb < BATCH; ++bb) {
            const double s1 = redd[0 + bb][0], q1 = redd[0 + bb][1];
            const double cnt = redd[0 + bb][2];          // stage-0 count
            const double s2 = redd[2 + bb][0], q2 = redd[2 + bb][1];
            const double den1 = q1 + cnt + (double)ORGANS * EPS;
            const double den2 = q2 + cnt + (double)ORGANS * EPS;
            total += 2.0 - (2.0 * s1 / den1 + 2.0 * s2 / den2);
        }
        *out = (float)(total / BATCH);
    }
}

extern "C" void kernel_launch(void* const* d_in, const int* in_sizes, int n_in,
                              void* d_out, int out_size, void* d_ws, size_t ws_size,
                              hipStream_t stream)
{
    const float* p1 = (const float*)d_in[0];
    const float* p2 = (const float*)d_in[1];
    const int* tg = (const int*)d_in[2];
    float* out = (float*)d_out;
    double* part = (double*)d_ws;    // 2048*3 doubles = 48 KB; all written per call

    dice_lds<<<dim3(NBLK), dim3(TPB), 0, stream>>>(p1, p2, tg, part);
    dice_final<<<1, 256, 0, stream>>>(part, out);
}

// Round 9
// 155.067 us; speedup vs baseline: 1.1197x; 1.1197x over previous
//
#include <hip/hip_runtime.h>

// DiceLoss: B=2, C=14, D=48, H=256, W=256, organs 1..13, weights all 1.0.
// Per batch b: S = sum of pred at target channel (t in 1..13),
//              Q = sum over c=1..13 of pred[c]^2, cnt = #{t>=1}.
// dice_stage = 2S/(Q + cnt + 13*EPS); out = mean_b(2 - dice1 - dice2).
//
// R9 = R6 (LDS ring, global_load_lds w16 aux=0, counted vmcnt(2), no
// barriers, 2048 blocks = 8/CU) with ONE axis changed: 4 interleaved
// streams per block instead of 2. Tile round-robin over
// {s1@cA, s2@cA, s1@cB, s2@cB}, cA=1..6, cB=7..12, channel 13 peeled on
// the cB walkers. The 3-deep in-flight set now always spans 3 distant
// regions -> more DRAM channel parallelism (R8's 1-stream was -25%,
// R6's 2-stream baseline 139us wall).

namespace {
constexpr int BATCH = 2;
constexpr int CH = 14;
constexpr int ORGANS = 13;
constexpr unsigned NV4 = 786432u;        // vec4 groups per (b, channel) slice
constexpr int TPB = 256;
constexpr int NBLK = 2048;               // 1024 windows per batch, 8/CU
constexpr unsigned WIN = 768u;           // groups per window (1024*768 = NV4)
constexpr int KT = 3;                    // tiles per (channel, stage)
constexpr double EPS = 1e-05;
}

// global -> LDS async, 16B/lane, default cache policy (NT hurt: R7).
#define LOADLDS(srcptr, slot)                                              \
    __builtin_amdgcn_global_load_lds(                                      \
        (const __attribute__((address_space(1))) unsigned*)(srcptr),       \
        (__attribute__((address_space(3))) unsigned*)&ring[(slot)][ldsq],  \
        16, 0, 0)

__global__ __launch_bounds__(TPB, 8) void dice_lds(
    const float* __restrict__ p1g, const float* __restrict__ p2g,
    const int* __restrict__ tg, double* __restrict__ part)
{
    __shared__ float4 ring[4][TPB];      // 16 KB ring, slot = tile & 3
    __shared__ float red[4][5];

    const unsigned blk = blockIdx.x;
    const unsigned b = blk >> 10;                // batch
    const unsigned w0 = (blk & 1023u) * WIN;     // window start (groups)
    const unsigned tid = threadIdx.x;
    const unsigned wid = tid >> 6;
    const unsigned ldsq = wid * 64u;             // this wave's ring quarter

    // 4 stream walkers (float4 idx space, + tid), advance NV4 per channel.
    const float4* wA0 = reinterpret_cast<const float4*>(p1g)
        + (unsigned long long)(b * CH + 1) * NV4 + w0 + tid;   // s1 @ cA
    const float4* wA1 = reinterpret_cast<const float4*>(p2g)
        + (unsigned long long)(b * CH + 1) * NV4 + w0 + tid;   // s2 @ cA
    const float4* wB0 = reinterpret_cast<const float4*>(p1g)
        + (unsigned long long)(b * CH + 7) * NV4 + w0 + tid;   // s1 @ cB
    const float4* wB1 = reinterpret_cast<const float4*>(p2g)
        + (unsigned long long)(b * CH + 7) * NV4 + w0 + tid;   // s2 @ cB

    // Target window once: KT int4 per thread; pack labels into bytes.
    unsigned tw[KT];
    float cn = 0.f;
    {
        const int4* __restrict__ pT =
            reinterpret_cast<const int4*>(tg) + b * NV4 + w0;
        #pragma unroll
        for (int k = 0; k < KT; ++k) {
            const int4 t = pT[k * TPB + tid];
            cn += (float)((t.x > 0) + (t.y > 0) + (t.z > 0) + (t.w > 0));
            tw[k] = (unsigned)t.x | ((unsigned)t.y << 8)
                  | ((unsigned)t.z << 16) | ((unsigned)t.w << 24);
        }
    }

    // Prologue: tiles 0,1,2 = (st0,k0),(st1,k0),(st2,k0).
    LOADLDS(wA0, 0);
    LOADLDS(wA1, 1);
    LOADLDS(wB0, 2);

    float s1 = 0.f, q1 = 0.f, s2 = 0.f, q2 = 0.f;
    unsigned cA = 1, cB = 7;

    auto acc4 = [&](const float4 A, const unsigned t4, const unsigned cc,
                    float& q, float& s) {
        q = fmaf(A.x, A.x, q); q = fmaf(A.y, A.y, q);
        q = fmaf(A.z, A.z, q); q = fmaf(A.w, A.w, q);
        const bool ex = ((t4 & 255u) == cc);
        const bool ey = (((t4 >> 8) & 255u) == cc);
        const bool ez = (((t4 >> 16) & 255u) == cc);
        const bool ew = ((t4 >> 24) == cc);
        s += (ex ? A.x : 0.f) + (ey ? A.y : 0.f)
           + (ez ? A.z : 0.f) + (ew ? A.w : 0.f);
    };

    // Main: 6 channel-pair iterations x 12 tiles. Position p: stream p&3,
    // k = p>>2, slot = p&3 (12 = 0 mod 4). Issue p+3; at p>=9 issue next
    // iteration's k=0 tiles (or channel-13 tiles on the last iteration).
    #pragma unroll 1
    for (int c6 = 0; c6 < 6; ++c6) {
        const bool last = (c6 == 5);
        #pragma unroll
        for (int p = 0; p < 12; ++p) {
            asm volatile("s_waitcnt vmcnt(2)" ::: "memory");
            if (p < 9) {
                const int st = (p + 3) & 3, kk = (p + 3) >> 2;
                const float4* base = (st == 0) ? wA0 : (st == 1) ? wA1
                                   : (st == 2) ? wB0 : wB1;
                LOADLDS(base + kk * TPB, (p + 3) & 3);
            } else if (!last) {
                const int st = p - 9;   // 0,1,2 -> next pair, k=0
                const float4* base = (st == 0) ? wA0 : (st == 1) ? wA1 : wB0;
                LOADLDS(base + NV4, (p + 3) & 3);
            } else {
                // channel-13 tiles 72..74: (s1,c13,k0),(s2,c13,k0),(s1,c13,k1)
                if (p == 9)  LOADLDS(wB0 + NV4, 0);
                if (p == 10) LOADLDS(wB1 + NV4, 1);
                if (p == 11) LOADLDS(wB0 + NV4 + TPB, 2);
            }
            {
                const int st = p & 3, kk = p >> 2;
                const unsigned cc = (st < 2) ? cA : cB;
                const float4 A = ring[p & 3][tid];
                if (st & 1) acc4(A, tw[kk], cc, q2, s2);
                else        acc4(A, tw[kk], cc, q1, s1);
            }
        }
        wA0 += NV4; wA1 += NV4; wB0 += NV4; wB1 += NV4; ++cA; ++cB;
    }

    // Tail: walkers now at cA=7... cB=13 (wB0/wB1 point at channel 13).
    // Consume tiles 72..77 (organ 13), issue 75..77, drain.
    asm volatile("s_waitcnt vmcnt(2)" ::: "memory");
    LOADLDS(wB1 + TPB, 3);                        // tile 75
    acc4(ring[0][tid], tw[0], 13u, q1, s1);       // tile 72
    asm volatile("s_waitcnt vmcnt(2)" ::: "memory");
    LOADLDS(wB0 + 2 * TPB, 0);                    // tile 76
    acc4(ring[1][tid], tw[0], 13u, q2, s2);       // tile 73
    asm volatile("s_waitcnt vmcnt(2)" ::: "memory");
    LOADLDS(wB1 + 2 * TPB, 1);                    // tile 77
    acc4(ring[2][tid], tw[1], 13u, q1, s1);       // tile 74
    asm volatile("s_waitcnt vmcnt(2)" ::: "memory");
    acc4(ring[3][tid], tw[1], 13u, q2, s2);       // tile 75
    asm volatile("s_waitcnt vmcnt(1)" ::: "memory");
    acc4(ring[0][tid], tw[2], 13u, q1, s1);       // tile 76
    asm volatile("s_waitcnt vmcnt(0)" ::: "memory");
    acc4(ring[1][tid], tw[2], 13u, q2, s2);       // tile 77

    // ---- Block reduction: wave shuffle then LDS across 4 waves ----
    float vals[5] = {s1, q1, s2, q2, cn};
    #pragma unroll
    for (int k = 0; k < 5; ++k) {
        float v = vals[k];
        #pragma unroll
        for (int off = 32; off > 0; off >>= 1) v += __shfl_down(v, off, 64);
        vals[k] = v;
    }
    const int lane = tid & 63;
    if (lane == 0) {
        #pragma unroll
        for (int k = 0; k < 5; ++k) red[wid][k] = vals[k];
    }
    __syncthreads();
    if (tid == 0) {
        #pragma unroll
        for (int k = 0; k < 5; ++k)
            part[blk * 5 + k] =
                (double)(red[0][k] + red[1][k] + red[2][k] + red[3][k]);
    }
}

__global__ __launch_bounds__(256) void dice_final(
    const double* __restrict__ part, float* __restrict__ out)
{
    __shared__ double redd[BATCH][4][5];
    const int tid = threadIdx.x, lane = tid & 63, wv = tid >> 6;
    #pragma unroll
    for (int b = 0; b < BATCH; ++b) {
        double loc[5] = {0, 0, 0, 0, 0};
        for (int i = tid; i < NBLK / BATCH; i += 256) {
            const double* p = part + ((unsigned)(b * (NBLK / BATCH) + i)) * 5u;
            #pragma unroll
            for (int k = 0; k < 5; ++k) loc[k] += p[k];
        }
        #pragma unroll
        for (int k = 0; k < 5; ++k) {
            double v = loc[k];
            #pragma unroll
            for (int off = 32; off > 0; off >>= 1) v += __shfl_down(v, off, 64);
            loc[k] = v;
        }
        if (lane == 0) {
            #pragma unroll
            for (int k = 0; k < 5; ++k) redd[b][wv][k] = loc[k];
        }
    }
    __syncthreads();
    if (tid == 0) {
        double total = 0.0;
        #pragma unroll
        for (int b = 0; b < BATCH; ++b) {
            double a[5];
            #pragma unroll
            for (int k = 0; k < 5; ++k)
                a[k] = redd[b][0][k] + redd[b][1][k] + redd[b][2][k] + redd[b][3][k];
            const double den1 = a[1] + a[4] + (double)ORGANS * EPS;
            const double den2 = a[3] + a[4] + (double)ORGANS * EPS;
            total += 2.0 - (2.0 * a[0] / den1 + 2.0 * a[2] / den2);
        }
        *out = (float)(total / BATCH);
    }
}

extern "C" void kernel_launch(void* const* d_in, const int* in_sizes, int n_in,
                              void* d_out, int out_size, void* d_ws, size_t ws_size,
                              hipStream_t stream)
{
    const float* p1 = (const float*)d_in[0];
    const float* p2 = (const float*)d_in[1];
    const int* tg = (const int*)d_in[2];
    float* out = (float*)d_out;
    double* part = (double*)d_ws;    // 2048*5 doubles = 80 KB; all written per call

    dice_lds<<<dim3(NBLK), dim3(TPB), 0, stream>>>(p1, p2, tg, part);
    dice_final<<<1, 256, 0, stream>>>(part, out);
}